// Round 7
// baseline (327.895 us; speedup 1.0000x reference)
//
#include <hip/hip_runtime.h>
#include <stdint.h>

#define N_SPK 512
#define N_UTT 64
#define DIM   1024
#define NROWS (N_SPK * N_UTT)   // 32768
#define EPS   1e-6f

#define BM  128
#define BN  128
#define BKB 128                 // K bytes (fp8 elems) per tile
#define KITERS (DIM / BKB)      // 8

typedef __attribute__((ext_vector_type(8))) int   int8v;
typedef __attribute__((ext_vector_type(4))) int   int4v;
typedef __attribute__((ext_vector_type(4))) float f32x4;

// K1: one block per speaker. Wave w streams its 16 rows in 2 rounds of 8
// (32 float4 loads in flight), writes fp8(e4m3) copy + per-row xx.
// Full centroid reduced in-block (LDS), normalized, written as 16*c_hat fp8
// (x16 dodges e4m3 subnormals; folded out as w/16 in the GEMM epilogue).
// Block 0 also zero-inits out[0] for finalize's atomicAdd (stream-ordered).
__global__ __launch_bounds__(256) void prep_full(
    const float* __restrict__ x, uint8_t* __restrict__ xb,
    uint8_t* __restrict__ cmat, float* __restrict__ xxg, float* __restrict__ ssqg,
    float* __restrict__ out)
{
    const int n    = blockIdx.x;
    const int tid  = threadIdx.x;
    const int lane = tid & 63;
    const int w    = tid >> 6;

    if (n == 0 && tid == 0) out[0] = 0.f;

    const float* xn  = x  + (size_t)n * N_UTT * DIM;
    uint8_t*     xbn = xb + (size_t)n * N_UTT * DIM;

    float Sp[16];
    #pragma unroll
    for (int j = 0; j < 16; ++j) Sp[j] = 0.f;

    for (int rnd = 0; rnd < 2; ++rnd) {
        const int m0 = w * 16 + rnd * 8;

        float4 v[32];
        #pragma unroll
        for (int i = 0; i < 8; ++i)
            #pragma unroll
            for (int j = 0; j < 4; ++j)
                v[i * 4 + j] = *(const float4*)(xn + (size_t)(m0 + i) * DIM + j * 256 + lane * 4);

        float xx[8];
        #pragma unroll
        for (int i = 0; i < 8; ++i) xx[i] = 0.f;

        #pragma unroll
        for (int i = 0; i < 8; ++i) {
            #pragma unroll
            for (int j = 0; j < 4; ++j) {
                const float4 q = v[i * 4 + j];
                xx[i] += q.x * q.x + q.y * q.y + q.z * q.z + q.w * q.w;
                Sp[j * 4 + 0] += q.x; Sp[j * 4 + 1] += q.y;
                Sp[j * 4 + 2] += q.z; Sp[j * 4 + 3] += q.w;
                uint32_t u = (uint32_t)__builtin_amdgcn_cvt_pk_fp8_f32(q.x, q.y, 0, false);
                u = (uint32_t)__builtin_amdgcn_cvt_pk_fp8_f32(q.z, q.w, (int)u, true);
                *(uint32_t*)(xbn + (size_t)(m0 + i) * DIM + j * 256 + lane * 4) = u;
            }
        }

        #pragma unroll
        for (int i = 0; i < 8; ++i) {
            float t = xx[i];
            #pragma unroll
            for (int off = 1; off < 64; off <<= 1) t += __shfl_xor(t, off);
            if (lane == 0) xxg[n * N_UTT + m0 + i] = t;
        }
    }

    // Block reduce of the 4 waves' partial centroids.
    __shared__ float Sh[4][DIM];   // 16 KB
    #pragma unroll
    for (int j = 0; j < 4; ++j)
        *(float4*)&Sh[w][j * 256 + lane * 4] =
            make_float4(Sp[j * 4], Sp[j * 4 + 1], Sp[j * 4 + 2], Sp[j * 4 + 3]);
    __syncthreads();

    const int d0 = tid * 4;
    float4 S = *(const float4*)&Sh[0][d0];
    {
        const float4 b1 = *(const float4*)&Sh[1][d0];
        const float4 b2 = *(const float4*)&Sh[2][d0];
        const float4 b3 = *(const float4*)&Sh[3][d0];
        S.x += b1.x + b2.x + b3.x; S.y += b1.y + b2.y + b3.y;
        S.z += b1.z + b2.z + b3.z; S.w += b1.w + b2.w + b3.w;
    }

    float css = S.x * S.x + S.y * S.y + S.z * S.z + S.w * S.w;
    #pragma unroll
    for (int off = 1; off < 64; off <<= 1) css += __shfl_xor(css, off);
    __shared__ float red[4];
    if ((tid & 63) == 0) red[tid >> 6] = css;
    __syncthreads();
    const float ssq = red[0] + red[1] + red[2] + red[3];

    const float scale = rsqrtf(fmaxf(ssq * (1.0f / 4096.f), EPS)) * (16.0f / 64.f);
    uint32_t u = (uint32_t)__builtin_amdgcn_cvt_pk_fp8_f32(S.x * scale, S.y * scale, 0, false);
    u = (uint32_t)__builtin_amdgcn_cvt_pk_fp8_f32(S.z * scale, S.w * scale, (int)u, true);
    *(uint32_t*)(cmat + (size_t)n * DIM + d0) = u;
    if (tid == 0) ssqg[n] = ssq;
}

// K2: MX-fp8 MFMA GEMM (A = xb [32768 x 1024] e4m3, B^T = cmat [512 x 1024]
// e4m3 = 16*c_hat), scales pinned to 1.0 (E8M0 0x7F). Persistent: 512 blocks,
// each does TWO col-tiles (rt, cpair*2+{0,1}) sequentially -> all blocks
// co-resident (no occupancy tail), prologue amortized, A-tile L2-hot.
// 128x128 tile, BK=128 B, 8 k-iters, global_load_lds width-16, XOR swizzle.
// Plain __launch_bounds__(256): the (256,3) min-waves arg clamped VGPR to 84
// in R5 -> acc spilled -> 1 GB scratch traffic. Never again.
__global__ __launch_bounds__(256) void gemm_lse_kernel(
    const uint8_t* __restrict__ xb, const uint8_t* __restrict__ cmat,
    const float* __restrict__ xxg, const float* __restrict__ ssqg,
    const float* __restrict__ wp, const float* __restrict__ bp,
    float* __restrict__ sumexp4, float* __restrict__ pos)
{
    __shared__ __align__(16) uint8_t Asm[BM * BKB];   // 16 KB
    __shared__ __align__(16) uint8_t Bsm[BN * BKB];   // 16 KB
    __shared__ float SeLDS[BM];

    const int tid   = threadIdx.x;
    const int lane  = tid & 63;
    const int wid   = tid >> 6;
    const int waveM = wid >> 1;
    const int waveN = wid & 1;

    // p -> rt (256 values), cpair (2). Blocks sharing rt are p and p+8
    // (same XCD under the %8 dispatch heuristic) for A-tile L2 locality.
    const int p     = blockIdx.x;
    const int rt    = (p & 7) | ((p >> 4) << 3);
    const int cpair = (p >> 3) & 1;
    const int rowBase = rt * BM;

    // Staging addressing: LDS slot s = i*256+tid (16 B each); row = s>>3,
    // slot-chunk s&7 holds global chunk h = (s&7)^(row&7). Since 256 = 0 mod 8,
    // h and the row-phase are i-invariant: inst i address = base + i*32*DIM.
    const int srow0 = tid >> 3;
    const int h     = (tid & 7) ^ (srow0 & 7);
    const uint8_t* gA0 = xb + (size_t)(rowBase + srow0) * DIM + h * 16;

    const int cL  = lane & 15;
    const int q   = lane >> 4;
    const int fs0 = (2 * q) ^ (cL & 7);   // swizzled slots for the 32B frag
    const int fs1 = fs0 ^ 1;

    const float wv0 = wp[0];
    const float wv  = wv0 * 0.0625f;      // fold the x16 centroid scale
    const float bv  = bp[0];

    for (int t = 0; t < 2; ++t) {
        const int ct      = cpair * 2 + t;
        const int colBase = ct * BN;
        const uint8_t* gB0 = cmat + (size_t)(colBase + srow0) * DIM + h * 16;

        f32x4 acc[4][4];
        #pragma unroll
        for (int i = 0; i < 4; ++i)
            #pragma unroll
            for (int j = 0; j < 4; ++j)
                acc[i][j] = (f32x4){0.f, 0.f, 0.f, 0.f};

        for (int kt = 0; kt < KITERS; ++kt) {
            __syncthreads();
            const int ko = kt * BKB;
            #pragma unroll
            for (int i = 0; i < 4; ++i) {
                __builtin_amdgcn_global_load_lds(
                    (const __attribute__((address_space(1))) void*)(gA0 + (size_t)i * 32 * DIM + ko),
                    (__attribute__((address_space(3))) void*)(&Asm[(i * 256 + wid * 64) * 16]),
                    16, 0, 0);
                __builtin_amdgcn_global_load_lds(
                    (const __attribute__((address_space(1))) void*)(gB0 + (size_t)i * 32 * DIM + ko),
                    (__attribute__((address_space(3))) void*)(&Bsm[(i * 256 + wid * 64) * 16]),
                    16, 0, 0);
            }
            __syncthreads();

            int8v b[4];
            #pragma unroll
            for (int bj = 0; bj < 4; ++bj) {
                const int row = waveN * 64 + bj * 16 + cL;
                const int4v lo = *(const int4v*)&Bsm[row * BKB + fs0 * 16];
                const int4v hi = *(const int4v*)&Bsm[row * BKB + fs1 * 16];
                b[bj] = __builtin_shufflevector(lo, hi, 0, 1, 2, 3, 4, 5, 6, 7);
            }

            #pragma unroll
            for (int bi = 0; bi < 4; ++bi) {
                const int row = waveM * 64 + bi * 16 + cL;
                const int4v lo = *(const int4v*)&Asm[row * BKB + fs0 * 16];
                const int4v hi = *(const int4v*)&Asm[row * BKB + fs1 * 16];
                const int8v a = __builtin_shufflevector(lo, hi, 0, 1, 2, 3, 4, 5, 6, 7);
                #pragma unroll
                for (int bj = 0; bj < 4; ++bj)
                    acc[bi][bj] = __builtin_amdgcn_mfma_scale_f32_16x16x128_f8f6f4(
                        a, b[bj], acc[bi][bj],
                        0, 0,                   // cbsz=FP8(e4m3), blgp=FP8(e4m3)
                        0, 0x7f7f7f7f,          // opsel_a, scale_a = 1.0
                        0, 0x7f7f7f7f);         // opsel_b, scale_b = 1.0
            }
        }

        // Epilogue for this ct. dot = 16 * (x . c_hat).
        float srow[16];
        #pragma unroll
        for (int bi = 0; bi < 4; ++bi) {
            #pragma unroll
            for (int r = 0; r < 4; ++r) {
                const int R     = rowBase + waveM * 64 + bi * 16 + q * 4 + r;
                const float xxv = xxg[R];
                const float rn  = rsqrtf(fmaxf(xxv, EPS));
                const int nrow  = R >> 6;
                float s = 0.f;
                #pragma unroll
                for (int bj = 0; bj < 4; ++bj) {
                    const int col = colBase + waveN * 64 + bj * 16 + cL;
                    const float dot = acc[bi][bj][r];
                    float sim;
                    if (col == nrow) {
                        const float ssqv = ssqg[nrow];
                        const float xs   = dot * sqrtf(ssqv) * 0.0625f;  // x . S
                        const float d2   = ssqv - 2.f * xs + xxv;
                        const float cs   = ((xs - xxv) * (1.f / 63.f)) * rn *
                                           rsqrtf(fmaxf(d2 * (1.f / 3969.f), EPS));
                        sim = wv0 * cs + bv;
                        pos[R] = sim;
                    } else {
                        sim = wv * dot * rn + bv;
                    }
                    s += __expf(sim);
                }
                #pragma unroll
                for (int off = 1; off < 16; off <<= 1) s += __shfl_xor(s, off);
                srow[bi * 4 + r] = s;
            }
        }

        if (waveN == 1 && cL == 0) {
            #pragma unroll
            for (int bi = 0; bi < 4; ++bi)
                #pragma unroll
                for (int r = 0; r < 4; ++r)
                    SeLDS[waveM * 64 + bi * 16 + q * 4 + r] = srow[bi * 4 + r];
        }
        __syncthreads();
        if (waveN == 0 && cL == 0) {
            #pragma unroll
            for (int bi = 0; bi < 4; ++bi)
                #pragma unroll
                for (int r = 0; r < 4; ++r) {
                    const int lr = waveM * 64 + bi * 16 + q * 4 + r;
                    sumexp4[(size_t)ct * NROWS + rowBase + lr] = srow[bi * 4 + r] + SeLDS[lr];
                }
        }
    }
}

// K3: 64 blocks; loss = sum_r log(sum_ct se4) - pos[r]; atomicAdd into out
// (zeroed by prep block 0, stream-ordered).
__global__ __launch_bounds__(256) void finalize_kernel(
    const float* __restrict__ pos, const float* __restrict__ se4,
    float* __restrict__ out)
{
    const int tid = blockIdx.x * 256 + threadIdx.x;
    float acc = 0.f;
    for (int r = tid; r < NROWS; r += 64 * 256) {
        const float s = se4[r] + se4[NROWS + r] + se4[2 * NROWS + r] + se4[3 * NROWS + r];
        acc += __logf(s) - pos[r];
    }
    #pragma unroll
    for (int off = 1; off < 64; off <<= 1) acc += __shfl_xor(acc, off);
    __shared__ float red[4];
    if ((threadIdx.x & 63) == 0) red[threadIdx.x >> 6] = acc;
    __syncthreads();
    if (threadIdx.x == 0)
        atomicAdd(out, red[0] + red[1] + red[2] + red[3]);
}

extern "C" void kernel_launch(void* const* d_in, const int* in_sizes, int n_in,
                              void* d_out, int out_size, void* d_ws, size_t ws_size,
                              hipStream_t stream)
{
    const float* x  = (const float*)d_in[0];
    const float* wp = (const float*)d_in[1];
    const float* bp = (const float*)d_in[2];
    float* out = (float*)d_out;

    char* ws = (char*)d_ws;
    size_t off = 0;
    uint8_t*  xb      = (uint8_t*)(ws + off); off += (size_t)NROWS * DIM;   // 32 MB
    uint8_t*  cmat    = (uint8_t*)(ws + off); off += (size_t)N_SPK * DIM;   // 0.5 MB
    float*    xxg     = (float*)(ws + off);   off += (size_t)NROWS * 4;
    float*    pos     = (float*)(ws + off);   off += (size_t)NROWS * 4;
    float*    sumexp4 = (float*)(ws + off);   off += (size_t)4 * NROWS * 4;
    float*    ssqg    = (float*)(ws + off);   off += (size_t)N_SPK * 4;

    prep_full<<<N_SPK, 256, 0, stream>>>(x, xb, cmat, xxg, ssqg, out);
    gemm_lse_kernel<<<(NROWS / BM) * 2, 256, 0, stream>>>(
        xb, cmat, xxg, ssqg, wp, bp, sumexp4, pos);
    finalize_kernel<<<64, 256, 0, stream>>>(pos, sumexp4, out);
}

// Round 8
// 272.825 us; speedup vs baseline: 1.2019x; 1.2019x over previous
//
#include <hip/hip_runtime.h>
#include <stdint.h>

#define N_SPK 512
#define N_UTT 64
#define DIM   1024
#define NROWS (N_SPK * N_UTT)   // 32768
#define EPS   1e-6f

#define KITERS 8                // K = 1024 / 128

typedef __attribute__((ext_vector_type(8))) int   int8v;
typedef __attribute__((ext_vector_type(4))) int   int4v;
typedef __attribute__((ext_vector_type(4))) float f32x4;

// K1: one block per speaker. Wave w streams its 16 rows in 2 rounds of 8
// (32 float4 loads in flight), writes fp8(e4m3) copy + per-row xx.
// Full centroid reduced in-block (LDS), normalized, written as 16*c_hat fp8
// (x16 dodges e4m3 subnormals; folded out as w/16 in the GEMM epilogue).
// Block 0 also zero-inits out[0] for finalize's atomicAdd (stream-ordered).
__global__ __launch_bounds__(256) void prep_full(
    const float* __restrict__ x, uint8_t* __restrict__ xb,
    uint8_t* __restrict__ cmat, float* __restrict__ xxg, float* __restrict__ ssqg,
    float* __restrict__ out)
{
    const int n    = blockIdx.x;
    const int tid  = threadIdx.x;
    const int lane = tid & 63;
    const int w    = tid >> 6;

    if (n == 0 && tid == 0) out[0] = 0.f;

    const float* xn  = x  + (size_t)n * N_UTT * DIM;
    uint8_t*     xbn = xb + (size_t)n * N_UTT * DIM;

    float Sp[16];
    #pragma unroll
    for (int j = 0; j < 16; ++j) Sp[j] = 0.f;

    for (int rnd = 0; rnd < 2; ++rnd) {
        const int m0 = w * 16 + rnd * 8;

        float4 v[32];
        #pragma unroll
        for (int i = 0; i < 8; ++i)
            #pragma unroll
            for (int j = 0; j < 4; ++j)
                v[i * 4 + j] = *(const float4*)(xn + (size_t)(m0 + i) * DIM + j * 256 + lane * 4);

        float xx[8];
        #pragma unroll
        for (int i = 0; i < 8; ++i) xx[i] = 0.f;

        #pragma unroll
        for (int i = 0; i < 8; ++i) {
            #pragma unroll
            for (int j = 0; j < 4; ++j) {
                const float4 q = v[i * 4 + j];
                xx[i] += q.x * q.x + q.y * q.y + q.z * q.z + q.w * q.w;
                Sp[j * 4 + 0] += q.x; Sp[j * 4 + 1] += q.y;
                Sp[j * 4 + 2] += q.z; Sp[j * 4 + 3] += q.w;
                uint32_t u = (uint32_t)__builtin_amdgcn_cvt_pk_fp8_f32(q.x, q.y, 0, false);
                u = (uint32_t)__builtin_amdgcn_cvt_pk_fp8_f32(q.z, q.w, (int)u, true);
                *(uint32_t*)(xbn + (size_t)(m0 + i) * DIM + j * 256 + lane * 4) = u;
            }
        }

        #pragma unroll
        for (int i = 0; i < 8; ++i) {
            float t = xx[i];
            #pragma unroll
            for (int off = 1; off < 64; off <<= 1) t += __shfl_xor(t, off);
            if (lane == 0) xxg[n * N_UTT + m0 + i] = t;
        }
    }

    // Block reduce of the 4 waves' partial centroids.
    __shared__ float Sh[4][DIM];   // 16 KB
    #pragma unroll
    for (int j = 0; j < 4; ++j)
        *(float4*)&Sh[w][j * 256 + lane * 4] =
            make_float4(Sp[j * 4], Sp[j * 4 + 1], Sp[j * 4 + 2], Sp[j * 4 + 3]);
    __syncthreads();

    const int d0 = tid * 4;
    float4 S = *(const float4*)&Sh[0][d0];
    {
        const float4 b1 = *(const float4*)&Sh[1][d0];
        const float4 b2 = *(const float4*)&Sh[2][d0];
        const float4 b3 = *(const float4*)&Sh[3][d0];
        S.x += b1.x + b2.x + b3.x; S.y += b1.y + b2.y + b3.y;
        S.z += b1.z + b2.z + b3.z; S.w += b1.w + b2.w + b3.w;
    }

    float css = S.x * S.x + S.y * S.y + S.z * S.z + S.w * S.w;
    #pragma unroll
    for (int off = 1; off < 64; off <<= 1) css += __shfl_xor(css, off);
    __shared__ float red[4];
    if ((tid & 63) == 0) red[tid >> 6] = css;
    __syncthreads();
    const float ssq = red[0] + red[1] + red[2] + red[3];

    const float scale = rsqrtf(fmaxf(ssq * (1.0f / 4096.f), EPS)) * (16.0f / 64.f);
    uint32_t u = (uint32_t)__builtin_amdgcn_cvt_pk_fp8_f32(S.x * scale, S.y * scale, 0, false);
    u = (uint32_t)__builtin_amdgcn_cvt_pk_fp8_f32(S.z * scale, S.w * scale, (int)u, true);
    *(uint32_t*)(cmat + (size_t)n * DIM + d0) = u;
    if (tid == 0) ssqg[n] = ssq;
}

// K2: LDS-free MX-fp8 GEMM. Each wave owns an independent 64x64 tile:
// A and B fragments are loaded DIRECTLY global->VGPR (per-lane dwordx4 pairs;
// lanes (cL,q) cover 16 rows x 128 contiguous bytes -> line-coalesced).
// No __syncthreads, no vmcnt(0) barrier drains, no LDS staging: the 8-iter
// K-loop is freely pipelined and 12+ independent waves/CU hide latency.
// Block = 4 waves = 4 adjacent 64-col chunks of one 64-row group (A shared
// via L1); blocks p and p+8 share the row group (same XCD under %8 dispatch).
// cmat (0.5 MB) is L2-resident chip-wide. Epilogue: per-wave row sums of
// exp -> sumexp8[ct64] slice, diag reconstructs cos_self -> pos.
// Plain __launch_bounds__(256): min-waves variants spilled in R5/R7.
__global__ __launch_bounds__(256) void gemm_lse_kernel(
    const uint8_t* __restrict__ xb, const uint8_t* __restrict__ cmat,
    const float* __restrict__ xxg, const float* __restrict__ ssqg,
    const float* __restrict__ wp, const float* __restrict__ bp,
    float* __restrict__ sumexp8, float* __restrict__ pos)
{
    const int tid  = threadIdx.x;
    const int lane = tid & 63;
    const int w    = tid >> 6;

    const int p       = blockIdx.x;
    const int rt      = (p & 7) | ((p >> 4) << 3);   // [0,512) 64-row group
    const int colHalf = (p >> 3) & 1;
    const int ct      = colHalf * 4 + w;             // [0,8) 64-col chunk
    const int rowBase = rt * 64;
    const int colBase = ct * 64;

    const int cL = lane & 15;
    const int q  = lane >> 4;

    // Lane's fragment base: row (+bi*16) at byte offset q*32 (+kt*128).
    const uint8_t* aBase = xb   + (size_t)(rowBase + cL) * DIM + q * 32;
    const uint8_t* bBase = cmat + (size_t)(colBase + cL) * DIM + q * 32;

    f32x4 acc[4][4];
    #pragma unroll
    for (int i = 0; i < 4; ++i)
        #pragma unroll
        for (int j = 0; j < 4; ++j)
            acc[i][j] = (f32x4){0.f, 0.f, 0.f, 0.f};

    #pragma unroll 1
    for (int kt = 0; kt < KITERS; ++kt) {
        const int ko = kt * 128;

        int8v b[4];
        #pragma unroll
        for (int bj = 0; bj < 4; ++bj) {
            const uint8_t* pB = bBase + (size_t)bj * 16 * DIM + ko;
            const int4v lo = *(const int4v*)pB;
            const int4v hi = *(const int4v*)(pB + 16);
            b[bj] = __builtin_shufflevector(lo, hi, 0, 1, 2, 3, 4, 5, 6, 7);
        }

        #pragma unroll
        for (int bi = 0; bi < 4; ++bi) {
            const uint8_t* pA = aBase + (size_t)bi * 16 * DIM + ko;
            const int4v lo = *(const int4v*)pA;
            const int4v hi = *(const int4v*)(pA + 16);
            const int8v a = __builtin_shufflevector(lo, hi, 0, 1, 2, 3, 4, 5, 6, 7);
            #pragma unroll
            for (int bj = 0; bj < 4; ++bj)
                acc[bi][bj] = __builtin_amdgcn_mfma_scale_f32_16x16x128_f8f6f4(
                    a, b[bj], acc[bi][bj],
                    0, 0,                   // cbsz=FP8(e4m3), blgp=FP8(e4m3)
                    0, 0x7f7f7f7f,          // opsel_a, scale_a = 1.0
                    0, 0x7f7f7f7f);         // opsel_b, scale_b = 1.0
        }
    }

    // Epilogue. dot = 16 * (x . c_hat); fold the x16 into w.
    const float wv0 = wp[0];
    const float wv  = wv0 * 0.0625f;
    const float bv  = bp[0];

    #pragma unroll
    for (int bi = 0; bi < 4; ++bi) {
        #pragma unroll
        for (int r = 0; r < 4; ++r) {
            const int R     = rowBase + bi * 16 + q * 4 + r;
            const float xxv = xxg[R];
            const float rn  = rsqrtf(fmaxf(xxv, EPS));
            const int nrow  = R >> 6;
            float s = 0.f;
            #pragma unroll
            for (int bj = 0; bj < 4; ++bj) {
                const int col = colBase + bj * 16 + cL;
                const float dot = acc[bi][bj][r];
                float sim;
                if (col == nrow) {
                    const float ssqv = ssqg[nrow];
                    const float xs   = dot * sqrtf(ssqv) * 0.0625f;  // x . S
                    const float d2   = ssqv - 2.f * xs + xxv;
                    const float cs   = ((xs - xxv) * (1.f / 63.f)) * rn *
                                       rsqrtf(fmaxf(d2 * (1.f / 3969.f), EPS));
                    sim = wv0 * cs + bv;
                    pos[R] = sim;
                } else {
                    sim = wv * dot * rn + bv;
                }
                s += __expf(sim);
            }
            #pragma unroll
            for (int off = 1; off < 16; off <<= 1) s += __shfl_xor(s, off);
            if (cL == 0) sumexp8[(size_t)ct * NROWS + R] = s;
        }
    }
}

// K3: 64 blocks; loss = sum_r log(sum_{ct} se8[ct][r]) - pos[r]; atomicAdd
// into out (zeroed by prep block 0, stream-ordered).
__global__ __launch_bounds__(256) void finalize_kernel(
    const float* __restrict__ pos, const float* __restrict__ se8,
    float* __restrict__ out)
{
    const int tid = blockIdx.x * 256 + threadIdx.x;
    float acc = 0.f;
    for (int r = tid; r < NROWS; r += 64 * 256) {
        float s = 0.f;
        #pragma unroll
        for (int c = 0; c < 8; ++c) s += se8[(size_t)c * NROWS + r];
        acc += __logf(s) - pos[r];
    }
    #pragma unroll
    for (int off = 1; off < 64; off <<= 1) acc += __shfl_xor(acc, off);
    __shared__ float red[4];
    if ((threadIdx.x & 63) == 0) red[threadIdx.x >> 6] = acc;
    __syncthreads();
    if (threadIdx.x == 0)
        atomicAdd(out, red[0] + red[1] + red[2] + red[3]);
}

extern "C" void kernel_launch(void* const* d_in, const int* in_sizes, int n_in,
                              void* d_out, int out_size, void* d_ws, size_t ws_size,
                              hipStream_t stream)
{
    const float* x  = (const float*)d_in[0];
    const float* wp = (const float*)d_in[1];
    const float* bp = (const float*)d_in[2];
    float* out = (float*)d_out;

    char* ws = (char*)d_ws;
    size_t off = 0;
    uint8_t*  xb      = (uint8_t*)(ws + off); off += (size_t)NROWS * DIM;   // 32 MB
    uint8_t*  cmat    = (uint8_t*)(ws + off); off += (size_t)N_SPK * DIM;   // 0.5 MB
    float*    xxg     = (float*)(ws + off);   off += (size_t)NROWS * 4;
    float*    pos     = (float*)(ws + off);   off += (size_t)NROWS * 4;
    float*    sumexp8 = (float*)(ws + off);   off += (size_t)8 * NROWS * 4; // 1 MB
    float*    ssqg    = (float*)(ws + off);   off += (size_t)N_SPK * 4;

    prep_full<<<N_SPK, 256, 0, stream>>>(x, xb, cmat, xxg, ssqg, out);
    gemm_lse_kernel<<<1024, 256, 0, stream>>>(
        xb, cmat, xxg, ssqg, wp, bp, sumexp8, pos);
    finalize_kernel<<<64, 256, 0, stream>>>(pos, sumexp8, out);
}